// Round 11
// baseline (85.303 us; speedup 1.0000x reference)
//
#include <hip/hip_runtime.h>

// uLSIF loss: out = mean_i[ -2*exp(x_i.a_i/T) + (sum_j exp(2*x_i.a_j/T) - exp(2*x_i.a_i/T))/(N-1) ]
// N=8192, D=128, T=128.
// Round-8 lesson: barrier-lockstep LDS pipeline is stall-bound (~30us gemm, MfmaUtil ~11%).
// This round: NO LDS, NO barriers. convert pre-packs x,a (f16, a scaled by C2) into
// MFMA fragment-major layout (16-row x 32-k fragment = contiguous 1KB, lane l at byte l*16).
// gemm: A-frags reg-cached once; B-frags stream global->reg via 3-slot rolling buffer
// (12 loads in flight/wave, compiler-derived counted vmcnt). exp2+sum epilogue per tile.
// diag: exact fp32/f64 from raw inputs, per-block partials. No same-address atomics.

#define NN 8192
#define DD 128

typedef __attribute__((ext_vector_type(4))) float f32x4;
typedef __attribute__((ext_vector_type(8))) _Float16 f16x8;

// ---------------- fragment-major pack: fp32 -> f16 ------------------------------
// frag f = rg*4 + ks (rg: 16-row group, ks: 32-f16 k-group). Slot: lane l holds
// rows rg*16+(l&15), k = ks*32+(l>>4)*8 .. +8. Byte addr = f*1024 + l*16.
// grid 1024x256: thread j -> matrix m=j>>17, slot jj=j&131071 (f=jj>>6, l=jj&63).
// One 16B store per thread, fully coalesced (64 lanes of same f -> contiguous 1KB).
__global__ void convert_kernel(const float4* __restrict__ x, const float4* __restrict__ a,
                               f16x8* __restrict__ xf, f16x8* __restrict__ af) {
    const float C2 = (float)(2.0 / (128.0 * 0.69314718055994530942));
    int j  = blockIdx.x * 256 + threadIdx.x;   // 0..262143
    int m  = j >> 17;                          // 0 = x, 1 = a
    int jj = j & 131071;
    int f  = jj >> 6;
    int l  = jj & 63;
    int rg = f >> 2, ks = f & 3;
    int row = rg * 16 + (l & 15);
    int kf  = ks * 32 + (l >> 4) * 8;          // f16 col index
    int base = row * 32 + (kf >> 2);           // float4 units
    const float4* in = m ? a : x;
    float4 v0 = in[base];
    float4 v1 = in[base + 1];
    float s = m ? C2 : 1.0f;
    f16x8 o;
    o[0] = (_Float16)(v0.x * s); o[1] = (_Float16)(v0.y * s);
    o[2] = (_Float16)(v0.z * s); o[3] = (_Float16)(v0.w * s);
    o[4] = (_Float16)(v1.x * s); o[5] = (_Float16)(v1.y * s);
    o[6] = (_Float16)(v1.z * s); o[7] = (_Float16)(v1.w * s);
    (m ? af : xf)[(size_t)f * 64 + l] = o;
}

// ---------------- exact fp32/f64 diagonal, per-block partials --------------------
// 1024 blocks x 256 threads; 8 rows per block, 32 threads per row.
__global__ void diag_kernel(const float4* __restrict__ x, const float4* __restrict__ a,
                            double* __restrict__ s1p, double* __restrict__ s3p) {
    int t = threadIdx.x;
    int row = blockIdx.x * 8 + (t >> 5);
    int c = t & 31;
    float4 xv = x[row * 32 + c];
    float4 av = a[row * 32 + c];
    float d = xv.x * av.x + xv.y * av.y + xv.z * av.z + xv.w * av.w;
#pragma unroll
    for (int off = 16; off > 0; off >>= 1) d += __shfl_down(d, off, 32);
    __shared__ double rr[8];
    if ((t & 31) == 0) rr[t >> 5] = exp((double)d * (1.0 / 128.0));
    __syncthreads();
    if (t == 0) {
        double s1 = 0.0, s3 = 0.0;
#pragma unroll
        for (int k = 0; k < 8; ++k) { s1 += rr[k]; s3 += rr[k] * rr[k]; }
        s1p[blockIdx.x] = s1;
        s3p[blockIdx.x] = s3;
    }
}

// ---------------- fused GEMM + exp2 + sum: no LDS, no barriers -------------------
// grid = 32 row-panels x 8 col-chunks = 256 blocks, 512 thr (8 waves, 4m x 2n).
// Wave owns 64 rows x 64 cols per tile; 8 tiles of 128 cols per block.
// A-frags (16 x 1KB) reg-cached once. B-frags: 3-slot rolling prefetch, 12 in flight.
__global__ __launch_bounds__(512, 2) void gemm_exp_sum(const f16x8* __restrict__ xf,
                                                       const f16x8* __restrict__ af,
                                                       double* __restrict__ s2p) {
    const int tid  = threadIdx.x;
    const int lane = tid & 63;
    const int wid  = tid >> 6;
    const int bm    = blockIdx.x >> 3;   // 32 row panels of 256
    const int chunk = blockIdx.x & 7;    // 8 col chunks of 1024
    const int wm = wid >> 1;             // 0..3
    const int wn = wid & 1;              // 0..1

    // ---- A fragments, loaded once (rows bm*256 + wm*64 + mi*16) ----
    const int fA0 = (bm * 16 + wm * 4) * 4;          // + mi*4 + ks
    f16x8 afr[4][4];
#pragma unroll
    for (int mi = 0; mi < 4; ++mi)
#pragma unroll
        for (int ks = 0; ks < 4; ++ks)
            afr[mi][ks] = xf[(size_t)(fA0 + mi * 4 + ks) * 64 + lane];

    // ---- B prologue: first 3 k-steps of tile 0 into the 3-slot buffer ----
    const int fB0 = (chunk * 64 + wn * 4) * 4;       // + t*32 + ni*4 + ks
    f16x8 bfr[3][4];
#pragma unroll
    for (int kk = 0; kk < 3; ++kk)
#pragma unroll
        for (int ni = 0; ni < 4; ++ni)
            bfr[kk][ni] = af[(size_t)(fB0 + ni * 4 + kk) * 64 + lane];

    f32x4 acc[4][4];
#pragma unroll
    for (int mi = 0; mi < 4; ++mi)
#pragma unroll
        for (int ni = 0; ni < 4; ++ni) acc[mi][ni] = f32x4{0.f, 0.f, 0.f, 0.f};
    float ls0 = 0.f, ls1 = 0.f, ls2 = 0.f, ls3 = 0.f;

    // ---- 32 k-steps (8 tiles x 4); fully unrolled so bfr indices are static ----
#pragma unroll
    for (int kk = 0; kk < 32; ++kk) {
        const int ks = kk & 3;
        const int sl = kk % 3;
#pragma unroll
        for (int mi = 0; mi < 4; ++mi)
#pragma unroll
            for (int ni = 0; ni < 4; ++ni)
                acc[mi][ni] = __builtin_amdgcn_mfma_f32_16x16x32_f16(
                    afr[mi][ks], bfr[sl][ni], acc[mi][ni], 0, 0, 0);
        if (kk + 3 < 32) {               // prefetch k-step kk+3 into the freed slot
            const int kn = kk + 3, tn = kn >> 2, ksn = kn & 3;
#pragma unroll
            for (int ni = 0; ni < 4; ++ni)
                bfr[sl][ni] = af[(size_t)(fB0 + tn * 32 + ni * 4 + ksn) * 64 + lane];
        }
        if (ks == 3) {                   // tile complete: exp2-accumulate, reset acc
#pragma unroll
            for (int mi = 0; mi < 4; ++mi)
#pragma unroll
                for (int ni = 0; ni < 4; ++ni) {
                    ls0 += __builtin_amdgcn_exp2f(acc[mi][ni][0]);
                    ls1 += __builtin_amdgcn_exp2f(acc[mi][ni][1]);
                    ls2 += __builtin_amdgcn_exp2f(acc[mi][ni][2]);
                    ls3 += __builtin_amdgcn_exp2f(acc[mi][ni][3]);
                    acc[mi][ni] = f32x4{0.f, 0.f, 0.f, 0.f};
                }
        }
    }

    float lsum = (ls0 + ls1) + (ls2 + ls3);
#pragma unroll
    for (int off = 32; off > 0; off >>= 1) lsum += __shfl_down(lsum, off);

    __shared__ double wred[8];
    if (lane == 0) wred[wid] = (double)lsum;
    __syncthreads();
    if (tid == 0) {
        double s = 0.0;
#pragma unroll
        for (int k = 0; k < 8; ++k) s += wred[k];
        s2p[blockIdx.x] = s;
    }
}

// ---------------- finalize: sum all partials -------------------------------------
__global__ void finalize_kernel(const double* __restrict__ s1p, const double* __restrict__ s3p,
                                const double* __restrict__ s2p, float* __restrict__ out) {
    int t = threadIdx.x;                // 1024 threads
    double v1 = s1p[t];
    double v3 = s3p[t];
    double v2 = (t < 256) ? s2p[t] : 0.0;
#pragma unroll
    for (int off = 32; off > 0; off >>= 1) {
        v1 += __shfl_down(v1, off);
        v3 += __shfl_down(v3, off);
        v2 += __shfl_down(v2, off);
    }
    __shared__ double r1[16], r2[16], r3[16];
    int wid = t >> 6, lane = t & 63;
    if (lane == 0) { r1[wid] = v1; r2[wid] = v2; r3[wid] = v3; }
    __syncthreads();
    if (t == 0) {
        double S1 = 0.0, S2 = 0.0, S3 = 0.0;
#pragma unroll
        for (int k = 0; k < 16; ++k) { S1 += r1[k]; S2 += r2[k]; S3 += r3[k]; }
        double res = (-2.0 * S1 + (S2 - S3) / (double)(NN - 1)) / (double)NN;
        out[0] = (float)res;
    }
}

extern "C" void kernel_launch(void* const* d_in, const int* in_sizes, int n_in,
                              void* d_out, int out_size, void* d_ws, size_t ws_size,
                              hipStream_t stream) {
    const float* x = (const float*)d_in[0];
    const float* a = (const float*)d_in[1];
    float* out = (float*)d_out;
    char* ws = (char*)d_ws;

    double* s1p = (double*)ws;                      // 1024 f64 = 8 KB
    double* s3p = (double*)(ws + 8192);             // 1024 f64 = 8 KB
    double* s2p = (double*)(ws + 16384);            // 256  f64 = 2 KB
    f16x8*  xf  = (f16x8*)(ws + 32768);             // 2 MB packed f16 x
    f16x8*  af  = (f16x8*)(ws + 32768 + (size_t)NN * DD * 2);  // 2 MB packed f16 a*C2

    convert_kernel<<<1024, 256, 0, stream>>>((const float4*)x, (const float4*)a, xf, af);
    diag_kernel<<<1024, 256, 0, stream>>>((const float4*)x, (const float4*)a, s1p, s3p);
    gemm_exp_sum<<<256, 512, 0, stream>>>(xf, af, s2p);
    finalize_kernel<<<1, 1024, 0, stream>>>(s1p, s3p, s2p, out);
}